// Round 5
// baseline (175.354 us; speedup 1.0000x reference)
//
#include <hip/hip_runtime.h>

// Problem constants
#define BB 16
#define TT 2000
#define DD 512
#define OO 41            // real output classes
#define CN 11
#define KTOT (CN * DD)   // 5632
#define NITER (CN * 16)  // 176 K-iterations of 32
#define NR (NITER / 2)   // 88 rounds of 2 K-iters
#define MT 48            // time steps per block (3 waves x 16 rows)
#define ROWS (MT + CN - 1) // 58 feature rows staged
#define NTHREADS 192     // 3 waves

typedef short short8 __attribute__((ext_vector_type(8)));
typedef float f32x4 __attribute__((ext_vector_type(4)));

__device__ __forceinline__ ushort f2bf(float f) {
    unsigned u = __builtin_bit_cast(unsigned, f);
    u += 0x7FFFu + ((u >> 16) & 1u);   // RNE; inputs are finite normals
    return (ushort)(u >> 16);
}

// async global->LDS, 16B per lane; LDS dest = wave-uniform base + lane*16
__device__ __forceinline__ void gll16(const ushort* gsrc, ushort* ldst) {
    auto* g = (const __attribute__((address_space(1))) unsigned int*)(gsrc);
    auto* l = (__attribute__((address_space(3))) unsigned int*)(ldst);
    __builtin_amdgcn_global_load_lds(g, l, 16, 0, 0);
}

// Relayout W (41x5632 f32) into MFMA-fragment-major bf16:
// chunk c = it*3 + nblk (it = j*16 + dc16; 176 iters; nblk 0..2)
// ushort offset = c*512 + lane*8 ; value = W[nblk*16 + (lane&15)]
//                                           [j*512 + dc16*32 + (lane>>4)*8 + i]
__global__ void prep_w_kernel(const float* __restrict__ W, ushort* __restrict__ Wf) {
    int tid = blockIdx.x * 256 + threadIdx.x;
    if (tid >= NITER * 3 * 64) return;
    int lane = tid & 63;
    int rest = tid >> 6;          // it*3 + nblk
    int nblk = rest % 3;
    int it   = rest / 3;
    int j    = it >> 4;
    int dc16 = it & 15;
    int row  = nblk * 16 + (lane & 15);
    int col  = j * DD + dc16 * 32 + (lane >> 4) * 8;
    short8 h = short8{0,0,0,0,0,0,0,0};
    if (row < OO) {
        const float* p = W + (size_t)row * KTOT + col;
        #pragma unroll
        for (int i = 0; i < 8; ++i) h[i] = (short)f2bf(p[i]);
    }
    *(short8*)(Wf + (size_t)tid * 8) = h;
}

__global__ __launch_bounds__(NTHREADS)
void conv_gemm_kernel(const float* __restrict__ F,
                      const ushort* __restrict__ Wfrag,
                      const float* __restrict__ bias,
                      float* __restrict__ out) {
    __shared__ ushort ldsA[ROWS * DD];    // 59392 B, XOR-swizzled
    __shared__ ushort ldsB[2 * 3072];     // 12288 B: 2 bufs x (2 iters x 3 chunks x 512)

    const int tid = threadIdx.x;
    const int b  = blockIdx.y;
    const int t0 = blockIdx.x * MT;
    const float* Fb = F + (size_t)b * TT * DD;
    const int wave = tid >> 6;
    const int lane = tid & 63;

    // ---- Issue B round-0 stage early (hides under A staging) ----
    {
        const ushort* g = Wfrag + lane * 8;
        gll16(g + (size_t)wave * 512,       ldsB + wave * 512);
        gll16(g + (size_t)(wave + 3) * 512, ldsB + (wave + 3) * 512);
    }

    // ---- Stage 58 feature rows (clipped) as bf16 into LDS ----
    for (int i = tid; i < ROWS * (DD / 4); i += NTHREADS) {
        int row = i >> 7;          // 128 float4 per row
        int c4  = i & 127;
        int t = t0 + row - 5;
        t = t < 0 ? 0 : (t > TT - 1 ? TT - 1 : t);
        float4 v = *(const float4*)(Fb + (size_t)t * DD + c4 * 4);
        ushort4 h;
        h.x = f2bf(v.x); h.y = f2bf(v.y); h.z = f2bf(v.z); h.w = f2bf(v.w);
        int base = row * 1024 + c4 * 8;
        *(ushort4*)((char*)ldsA + (base ^ ((row & 7) << 4))) = h;
    }
    asm volatile("s_waitcnt lgkmcnt(0)" ::: "memory");  // my ds_writes done

    const int lrow = lane & 15;
    const int lk   = lane >> 4;

    f32x4 acc0 = {0.f, 0.f, 0.f, 0.f};
    f32x4 acc1 = {0.f, 0.f, 0.f, 0.f};
    f32x4 acc2 = {0.f, 0.f, 0.f, 0.f};

    // ---- Pipelined K loop: 88 rounds x 2 iters; counted vmcnt, raw barriers ----
    for (int r = 0; r < NR; ++r) {
        // top barrier: everyone done computing round r-1 -> safe to overwrite buf[(r+1)&1]
        __builtin_amdgcn_s_barrier();
        __builtin_amdgcn_sched_barrier(0);
        if (r + 1 < NR) {
            const ushort* g = Wfrag + (size_t)(r + 1) * 3072 + lane * 8;
            ushort* l = ldsB + ((r + 1) & 1) * 3072;
            gll16(g + (size_t)wave * 512,       l + wave * 512);
            gll16(g + (size_t)(wave + 3) * 512, l + (wave + 3) * 512);
            asm volatile("s_waitcnt vmcnt(2)" ::: "memory");   // round r's 2 loads done
        } else {
            asm volatile("s_waitcnt vmcnt(0)" ::: "memory");   // final round: drain
        }
        __builtin_amdgcn_s_barrier();       // all waves' stage of round r visible
        __builtin_amdgcn_sched_barrier(0);  // don't hoist ds_reads above barrier

        const ushort* bb = ldsB + (r & 1) * 3072;
        #pragma unroll
        for (int s = 0; s < 2; ++s) {
            const int it = 2 * r + s;
            const int j  = it >> 4;
            const int dc = (it & 15) * 32;
            const int rrow = wave * 16 + lrow + 10 - j;
            const char* arow = (const char*)ldsA + rrow * 1024;
            const int cb = (dc + lk * 8) * 2;
            short8 a  = *(const short8*)(arow + (cb ^ ((rrow & 7) << 4)));
            short8 b0 = *(const short8*)(bb + s * 1536 + lane * 8);
            short8 b1 = *(const short8*)(bb + s * 1536 + 512 + lane * 8);
            short8 b2 = *(const short8*)(bb + s * 1536 + 1024 + lane * 8);
            acc0 = __builtin_amdgcn_mfma_f32_16x16x32_bf16(a, b0, acc0, 0, 0, 0);
            acc1 = __builtin_amdgcn_mfma_f32_16x16x32_bf16(a, b1, acc1, 0, 0, 0);
            acc2 = __builtin_amdgcn_mfma_f32_16x16x32_bf16(a, b2, acc2, 0, 0, 0);
        }
    }

    // ---- Epilogue: C[row=(lane>>4)*4+q][col=lane&15], add bias, masked store ----
    const float bias0 = bias[lrow];
    const float bias1 = bias[16 + lrow];
    const float bias2 = (32 + lrow < OO) ? bias[32 + lrow] : 0.f;
    const int tbase = t0 + wave * 16 + lk * 4;
    float* outb = out + (size_t)b * TT * OO;
    #pragma unroll
    for (int q = 0; q < 4; ++q) {
        const int t = tbase + q;
        if (t < TT) {
            float* po = outb + (size_t)t * OO;
            po[lrow]      = acc0[q] + bias0;
            po[16 + lrow] = acc1[q] + bias1;
            if (32 + lrow < OO) po[32 + lrow] = acc2[q] + bias2;
        }
    }
}

extern "C" void kernel_launch(void* const* d_in, const int* in_sizes, int n_in,
                              void* d_out, int out_size, void* d_ws, size_t ws_size,
                              hipStream_t stream) {
    const float* F    = (const float*)d_in[0];
    const float* W    = (const float*)d_in[1];
    const float* bias = (const float*)d_in[2];
    float* out = (float*)d_out;

    const dim3 grid((TT + MT - 1) / MT, BB);   // 42 x 16 = 672 blocks

    ushort* Wb = (ushort*)d_ws;                 // 540672 B needed; ws is larger
    const int prep_threads = NITER * 3 * 64;    // 33792
    prep_w_kernel<<<(prep_threads + 255) / 256, 256, 0, stream>>>(W, Wb);
    conv_gemm_kernel<<<grid, NTHREADS, 0, stream>>>(F, Wb, bias, out);
}

// Round 7
// 140.946 us; speedup vs baseline: 1.2441x; 1.2441x over previous
//
#include <hip/hip_runtime.h>

// Problem constants
#define BB 16
#define TT 2000
#define DD 512
#define OO 41              // real output classes
#define CN 11
#define KTOT (CN * DD)     // 5632
#define MT 64              // time steps per block (4 waves x 16 rows)
#define ROWS (MT + CN - 1) // 74 feature rows staged
#define HALF 256           // D-split half width (split-K over D)
#define NIT 88             // K-iters per split: 11 frames x 8 chunks of 32
#define NTHREADS 256       // 4 waves

typedef short short8 __attribute__((ext_vector_type(8)));
typedef float f32x4 __attribute__((ext_vector_type(4)));

__device__ __forceinline__ ushort f2bf(float f) {
    unsigned u = __builtin_bit_cast(unsigned, f);
    u += 0x7FFFu + ((u >> 16) & 1u);   // RNE; inputs are finite normals
    return (ushort)(u >> 16);
}

// Relayout W (41x5632 f32) into MFMA-fragment-major bf16, split-aware:
// chunk c = (split*88 + i)*3 + nblk ; ushort offset = c*512 + lane*8
// value = W[nblk*16 + (lane&15)][ (i>>3)*512 + split*256 + (i&7)*32 + (lane>>4)*8 + e ]
__global__ void prep_w_kernel(const float* __restrict__ W, ushort* __restrict__ Wf) {
    int tid = blockIdx.x * 256 + threadIdx.x;
    if (tid >= 176 * 3 * 64) return;
    int lane = tid & 63;
    int c    = tid >> 6;          // 0..527
    int nblk = c % 3;
    int itg  = c / 3;             // 0..175 = split*88 + i
    int split = itg / NIT;
    int i     = itg % NIT;
    int j    = i >> 3;
    int dcq  = i & 7;
    int row  = nblk * 16 + (lane & 15);
    int col  = j * DD + split * HALF + dcq * 32 + (lane >> 4) * 8;
    short8 h = short8{0,0,0,0,0,0,0,0};
    if (row < OO) {
        const float* p = W + (size_t)row * KTOT + col;
        #pragma unroll
        for (int e = 0; e < 8; ++e) h[e] = (short)f2bf(p[e]);
    }
    *(short8*)(Wf + (size_t)tid * 8) = h;
}

__global__ __launch_bounds__(NTHREADS, 4)
void conv_gemm_kernel(const float* __restrict__ F,
                      const ushort* __restrict__ Wfrag,
                      const float* __restrict__ bias,
                      float* __restrict__ out) {
    __shared__ ushort ldsA[ROWS * HALF];   // 37888 B -> 4 blocks/CU

    const int tid   = threadIdx.x;
    const int b     = blockIdx.y;
    const int t0    = blockIdx.x * MT;
    const int split = blockIdx.z;
    const float* Fb = F + (size_t)b * TT * DD + split * HALF;

    // ---- Stage 74 half-rows (clipped) as bf16 into LDS, XOR-swizzled ----
    for (int i = tid; i < ROWS * (HALF / 4); i += NTHREADS) {
        int row = i >> 6;          // 64 float4 per half-row
        int c4  = i & 63;
        int t = t0 + row - 5;
        t = t < 0 ? 0 : (t > TT - 1 ? TT - 1 : t);
        float4 v = *(const float4*)(Fb + (size_t)t * DD + c4 * 4);
        ushort4 h;
        h.x = f2bf(v.x); h.y = f2bf(v.y); h.z = f2bf(v.z); h.w = f2bf(v.w);
        int base = row * 512 + c4 * 8;   // bytes; half-row pitch = 512 B
        *(ushort4*)((char*)ldsA + (base ^ ((row & 7) << 4))) = h;
    }
    __syncthreads();

    const int wave = tid >> 6;
    const int lane = tid & 63;
    const int lrow = lane & 15;
    const int lk   = lane >> 4;
    const int am   = wave * 16 + lrow + 10;   // A row = am - j

    // A-frag fetch from LDS (swizzled)
    auto LDA = [&](int i) -> short8 {
        int r = am - (i >> 3);
        int byteoff = r * 512 + (((i & 7) * 32 + lk * 8) << 1);
        return *(const short8*)((const char*)ldsA + (byteoff ^ ((r & 7) << 4)));
    };

    const ushort* wp = Wfrag + (size_t)(split * NIT) * 1536 + lane * 8;

    f32x4 acc0 = {0.f, 0.f, 0.f, 0.f};
    f32x4 acc1 = {0.f, 0.f, 0.f, 0.f};
    f32x4 acc2 = {0.f, 0.f, 0.f, 0.f};

    // ---- 2-deep register-pipelined K loop, no barriers ----
    short8 a0 = LDA(0), a1 = LDA(1);
    short8 b00 = *(const short8*)(wp);
    short8 b01 = *(const short8*)(wp + 512);
    short8 b02 = *(const short8*)(wp + 1024);
    short8 b10 = *(const short8*)(wp + 1536);
    short8 b11 = *(const short8*)(wp + 2048);
    short8 b12 = *(const short8*)(wp + 2560);

    for (int i = 0; i < NIT; i += 2) {
        acc0 = __builtin_amdgcn_mfma_f32_16x16x32_bf16(a0, b00, acc0, 0, 0, 0);
        acc1 = __builtin_amdgcn_mfma_f32_16x16x32_bf16(a0, b01, acc1, 0, 0, 0);
        acc2 = __builtin_amdgcn_mfma_f32_16x16x32_bf16(a0, b02, acc2, 0, 0, 0);
        if (i + 2 < NIT) {
            const ushort* q = wp + 2 * 1536;
            a0  = LDA(i + 2);
            b00 = *(const short8*)(q);
            b01 = *(const short8*)(q + 512);
            b02 = *(const short8*)(q + 1024);
        }
        acc0 = __builtin_amdgcn_mfma_f32_16x16x32_bf16(a1, b10, acc0, 0, 0, 0);
        acc1 = __builtin_amdgcn_mfma_f32_16x16x32_bf16(a1, b11, acc1, 0, 0, 0);
        acc2 = __builtin_amdgcn_mfma_f32_16x16x32_bf16(a1, b12, acc2, 0, 0, 0);
        if (i + 3 < NIT) {
            const ushort* q = wp + 3 * 1536;
            a1  = LDA(i + 3);
            b10 = *(const short8*)(q);
            b11 = *(const short8*)(q + 512);
            b12 = *(const short8*)(q + 1024);   // FIXED: was q+2048 (wrong chunk)
        }
        wp += 2 * 1536;
    }

    // ---- Epilogue: C[row=lk*4+q][col], atomicAdd partials; split 0 adds bias ----
    const float bias0 = (split == 0) ? bias[lrow] : 0.f;
    const float bias1 = (split == 0) ? bias[16 + lrow] : 0.f;
    const float bias2 = (split == 0 && 32 + lrow < OO) ? bias[32 + lrow] : 0.f;
    const int tbase = t0 + wave * 16 + lk * 4;
    float* outb = out + (size_t)b * TT * OO;
    #pragma unroll
    for (int q = 0; q < 4; ++q) {
        const int t = tbase + q;
        if (t < TT) {
            float* po = outb + (size_t)t * OO;
            atomicAdd(po + lrow,      acc0[q] + bias0);
            atomicAdd(po + 16 + lrow, acc1[q] + bias1);
            if (32 + lrow < OO) atomicAdd(po + 32 + lrow, acc2[q] + bias2);
        }
    }
}

extern "C" void kernel_launch(void* const* d_in, const int* in_sizes, int n_in,
                              void* d_out, int out_size, void* d_ws, size_t ws_size,
                              hipStream_t stream) {
    const float* F    = (const float*)d_in[0];
    const float* W    = (const float*)d_in[1];
    const float* bias = (const float*)d_in[2];
    float* out = (float*)d_out;

    ushort* Wb = (ushort*)d_ws;                 // 540672 B needed
    const int prep_threads = 176 * 3 * 64;      // 33792
    prep_w_kernel<<<(prep_threads + 255) / 256, 256, 0, stream>>>(W, Wb);

    const dim3 grid(TT / MT + (TT % MT ? 1 : 0), BB, 2);   // 32 x 16 x 2 = 1024 blocks
    conv_gemm_kernel<<<grid, NTHREADS, 0, stream>>>(F, Wb, bias, out);
}